// Round 1
// baseline (209.511 us; speedup 1.0000x reference)
//
#include <hip/hip_runtime.h>
#include <math.h>

#define NM 5
#define NBATCH 65536
#define NCHUNK (NM * 10)   // 10 chunks per model: 4 (W1) + 4 (W2) + 2 (W3 padded to 64 rows)

typedef float f32x16 __attribute__((ext_vector_type(16)));
typedef float f32x4  __attribute__((ext_vector_type(4)));
typedef short short8 __attribute__((ext_vector_type(8)));
typedef unsigned int uint4v __attribute__((ext_vector_type(4)));
typedef unsigned int uint2v __attribute__((ext_vector_type(2)));

__device__ __forceinline__ short8 u2s(uint4v v) { union { uint4v u; short8 s; } t; t.u = v; return t.s; }

// exchange: a' = [h0: a | h1: b@h0], b' = [h0: a@h1 | h1: b]
__device__ __forceinline__ void plswap(unsigned &a, unsigned &b) {
#if __has_builtin(__builtin_amdgcn_permlane32_swap)
  uint2v r = __builtin_amdgcn_permlane32_swap(a, b, false, false);
  a = r[0]; b = r[1];
#else
  unsigned ta = (unsigned)__shfl_xor((int)a, 32, 64);
  unsigned tb = (unsigned)__shfl_xor((int)b, 32, 64);
  bool h0 = ((threadIdx.x & 63) < 32);
  unsigned na = h0 ? a : tb;
  unsigned nb = h0 ? ta : b;
  a = na; b = nb;
#endif
}

// ---------------- prep: split fp32 weights into hi/lo truncated-bf16 LDS-image in ws ----
// image: per model 163840 B; chunk c in 0..9, 16 KiB each: [hi 8 KiB][lo 8 KiB]
// plane byte(g_rel, h) = g_rel*256 + (((h>>3) ^ (g_rel & 15)) << 4) + (h&7)*2
__global__ void prep_weights(const float* __restrict__ W1, const float* __restrict__ W2,
                             const float* __restrict__ W3, unsigned short* __restrict__ img) {
  int id = blockIdx.x * 256 + threadIdx.x;
  if (id >= NM * 10 * 32 * 128) return;
  int m = id / 40960; int r = id % 40960;
  int c = r / 4096;   int r2 = r % 4096;
  int g_rel = r2 / 128; int h = r2 % 128;
  float v = 0.0f;
  if (c < 4)      { int g = c * 32 + g_rel;            v = W1[((size_t)m * 128 + g) * 128 + h]; }
  else if (c < 8) { int g = (c - 4) * 32 + g_rel;      v = W2[((size_t)m * 128 + g) * 128 + h]; }
  else            { int g = (c - 8) * 32 + g_rel; if (g < 36) v = W3[((size_t)m * 36 + g) * 128 + h]; }
  unsigned u  = __float_as_uint(v);
  unsigned hu = u & 0xFFFF0000u;
  float lo    = v - __uint_as_float(hu);
  unsigned lu = __float_as_uint(lo);
  int off = g_rel * 256 + (((h >> 3) ^ (g_rel & 15)) << 4) + (h & 7) * 2;
  size_t base = (size_t)m * 163840 + (size_t)c * 16384;
  img[(base + off) >> 1]        = (unsigned short)(hu >> 16);
  img[(base + 8192 + off) >> 1] = (unsigned short)(lu >> 16);
}

// ---------------- one GEMM layer: acc[mf] (32 rows each) = Wchunk * B + bias ------------
template <int MF, typename StageF>
__device__ __forceinline__ void run_layer(int cbase, const float* bias,
                                          const uint4v* Bh, const uint4v* Bl,
                                          f32x16* acc, int l31, int half,
                                          const unsigned char (*wbuf)[16384],
                                          StageF&& stage) {
#pragma unroll
  for (int mf = 0; mf < MF; ++mf) {
    const int c = cbase + mf;
    stage(c + 1);                       // prefetch next chunk into other buffer
    f32x16 aA, aB;
#pragma unroll
    for (int i = 0; i < 16; ++i) { aA[i] = 0.0f; aB[i] = 0.0f; }
    if (bias) {
#pragma unroll
      for (int q = 0; q < 4; ++q) {     // row = (i&3) + 8*(i>>2) + 4*half
        f32x4 bq = *(const f32x4*)(bias + mf * 32 + q * 8 + half * 4);
#pragma unroll
        for (int r = 0; r < 4; ++r) aA[4 * q + r] = bq[r];
      }
    }
    const unsigned char* rowp = &wbuf[c & 1][0] + l31 * 256;
#pragma unroll
    for (int kk = 0; kk < 8; ++kk) {
      const int sl = (((2 * kk + half) ^ (l31 & 15)) << 4);
      short8 Ah = *(const short8*)(rowp + sl);
      short8 Al = *(const short8*)(rowp + 8192 + sl);
      if ((kk & 1) == 0) {              // two independent chains break MFMA dep-stalls
        aA = __builtin_amdgcn_mfma_f32_32x32x16_bf16(Ah, u2s(Bh[kk]), aA, 0, 0, 0);
        aA = __builtin_amdgcn_mfma_f32_32x32x16_bf16(Ah, u2s(Bl[kk]), aA, 0, 0, 0);
        aA = __builtin_amdgcn_mfma_f32_32x32x16_bf16(Al, u2s(Bh[kk]), aA, 0, 0, 0);
      } else {
        aB = __builtin_amdgcn_mfma_f32_32x32x16_bf16(Ah, u2s(Bh[kk]), aB, 0, 0, 0);
        aB = __builtin_amdgcn_mfma_f32_32x32x16_bf16(Ah, u2s(Bl[kk]), aB, 0, 0, 0);
        aB = __builtin_amdgcn_mfma_f32_32x32x16_bf16(Al, u2s(Bh[kk]), aB, 0, 0, 0);
      }
    }
#pragma unroll
    for (int i = 0; i < 16; ++i) acc[mf][i] = aA[i] + aB[i];
    __syncthreads();                    // drains our staged loads + releases old buffer
  }
}

// ---------------- C/D accumulators -> next layer's B fragments (hi/lo bf16) ------------
template <int MF, bool RELU>
__device__ __forceinline__ void cvt_to_B(const f32x16* acc, uint4v* Bh, uint4v* Bl) {
#pragma unroll
  for (int mf = 0; mf < MF; ++mf) {
#pragma unroll
    for (int s = 0; s < 2; ++s) {       // kstep 2*mf+s from regs 8s..8s+7
      unsigned hu[8], lu[8];
#pragma unroll
      for (int i = 0; i < 8; ++i) {
        float v = acc[mf][8 * s + i];
        if (RELU) v = fmaxf(v, 0.0f);
        unsigned u = __float_as_uint(v);
        unsigned h = u & 0xFFFF0000u;
        hu[i] = h;
        lu[i] = __float_as_uint(v - __uint_as_float(h));
      }
      unsigned a0 = (hu[0] >> 16) | hu[1], a1 = (hu[2] >> 16) | hu[3];
      unsigned a2 = (hu[4] >> 16) | hu[5], a3 = (hu[6] >> 16) | hu[7];
      plswap(a0, a2); plswap(a1, a3);
      unsigned c0 = (lu[0] >> 16) | (lu[1] & 0xFFFF0000u), c1 = (lu[2] >> 16) | (lu[3] & 0xFFFF0000u);
      unsigned c2 = (lu[4] >> 16) | (lu[5] & 0xFFFF0000u), c3 = (lu[6] >> 16) | (lu[7] & 0xFFFF0000u);
      plswap(c0, c2); plswap(c1, c3);
      Bh[2 * mf + s] = uint4v{a0, a1, a2, a3};
      Bl[2 * mf + s] = uint4v{c0, c1, c2, c3};
    }
  }
}

// ---------------- main fused kernel ----------------------------------------------------
__global__ __launch_bounds__(256, 2)
void ens_mlp(const float* __restrict__ x,  const float* __restrict__ b1,
             const float* __restrict__ b2, const float* __restrict__ b3,
             const unsigned char* __restrict__ img, float* __restrict__ out) {
  __shared__ __align__(16) unsigned char wbuf[2][16384];   // 32 KiB W-chunk double buffer
  __shared__ float ybuf[128][36];                          // 18 KiB per-model y transpose

  const int tid  = threadIdx.x;
  const int lane = tid & 63;
  const int wv   = tid >> 6;
  const int l31  = lane & 31;
  const int half = lane >> 5;
  const int b_loc = wv * 32 + l31;
  const size_t b_glob = (size_t)blockIdx.x * 128 + b_loc;

  auto stage = [&](int j) {
    if (j >= NCHUNK) return;
    const unsigned char* src = img + (size_t)(j / 10) * 163840 + (size_t)(j % 10) * 16384;
    unsigned char* dst = &wbuf[j & 1][0];
#pragma unroll
    for (int i = 0; i < 4; ++i) {
      int off = i * 4096 + wv * 1024;   // dest: wave-uniform base + lane*16 (linear image)
      __builtin_amdgcn_global_load_lds(
          (const __attribute__((address_space(1))) unsigned int*)(src + off + lane * 16),
          (__attribute__((address_space(3))) unsigned int*)(dst + off),
          16, 0, 0);
    }
  };

  stage(0);

  // x fragments (layer-1 B operand), hi/lo truncated-bf16, resident for all 5 models.
  uint4v xh[8], xl[8];
  {
    const float* xrow = x + b_glob * 128 + half * 8;
#pragma unroll
    for (int kk = 0; kk < 8; ++kk) {
      f32x4 f0 = *(const f32x4*)(xrow + kk * 16);
      f32x4 f1 = *(const f32x4*)(xrow + kk * 16 + 4);
      float f[8] = {f0[0], f0[1], f0[2], f0[3], f1[0], f1[1], f1[2], f1[3]};
      uint4v hw, lw;
#pragma unroll
      for (int jj = 0; jj < 4; ++jj) {
        unsigned ua = __float_as_uint(f[2 * jj]), ub = __float_as_uint(f[2 * jj + 1]);
        unsigned ha = ua & 0xFFFF0000u, hb = ub & 0xFFFF0000u;
        float la = f[2 * jj] - __uint_as_float(ha);
        float lb = f[2 * jj + 1] - __uint_as_float(hb);
        hw[jj] = (ha >> 16) | hb;
        lw[jj] = (__float_as_uint(la) >> 16) | (__float_as_uint(lb) & 0xFFFF0000u);
      }
      xh[kk] = hw; xl[kk] = lw;
    }
  }
  __syncthreads();   // chunk 0 ready

  float sm[9], sv[9];
#pragma unroll
  for (int i = 0; i < 9; ++i) { sm[i] = 0.0f; sv[i] = 0.0f; }

  for (int m = 0; m < NM; ++m) {
    const int c0 = m * 10;

    f32x16 acc1[4];
    run_layer<4>(c0, b1 + m * 128, xh, xl, acc1, l31, half, wbuf, stage);
    uint4v B2h[8], B2l[8];
    cvt_to_B<4, true>(acc1, B2h, B2l);

    f32x16 acc2[4];
    run_layer<4>(c0 + 4, b2 + m * 128, B2h, B2l, acc2, l31, half, wbuf, stage);
    uint4v B3h[8], B3l[8];
    cvt_to_B<4, true>(acc2, B3h, B3l);

    f32x16 acc3[2];
    run_layer<2>(c0 + 8, (const float*)nullptr, B3h, B3l, acc3, l31, half, wbuf, stage);

    // ---- epilogue: transpose y through LDS, combine across models --------------------
#pragma unroll
    for (int i = 0; i < 16; ++i) {
      int o = (i & 3) + 8 * (i >> 2) + 4 * half;   // 0..31
      ybuf[b_loc][o] = acc3[0][i];
    }
    if (half == 0) {
#pragma unroll
      for (int i = 0; i < 4; ++i) ybuf[b_loc][32 + i] = acc3[1][i];   // o = 32..35
    }
    __syncthreads();
    const float* b3m = b3 + m * 36;
#pragma unroll
    for (int i = 0; i < 9; ++i) {
      int e = tid + 256 * i;            // 2304 = 128 rows * 18 outputs
      int r = e / 18, o = e - 18 * r;
      float ym = ybuf[r][o] + b3m[o];
      float yv = ybuf[r][o + 18] + b3m[o + 18];
      float sp = fmaxf(yv, 0.0f) + log1pf(expf(-fabsf(yv)));   // stable softplus
      sm[i] += ym;
      sv[i] += sp + 1e-6f + ym * ym;
    }
    __syncthreads();                    // release ybuf for next model
  }

  const size_t rbase = (size_t)blockIdx.x * 128 * 18;
#pragma unroll
  for (int i = 0; i < 9; ++i) {
    int e = tid + 256 * i;
    float mean = sm[i] * 0.2f;
    float var  = fmaxf(sv[i] * 0.2f - mean * mean, 0.0f) + 1e-6f;
    out[rbase + e] = mean;
    out[(size_t)NBATCH * 18 + rbase + e] = var;
  }
}

// ---------------- launcher -------------------------------------------------------------
extern "C" void kernel_launch(void* const* d_in, const int* in_sizes, int n_in,
                              void* d_out, int out_size, void* d_ws, size_t ws_size,
                              hipStream_t stream) {
  const float* x  = (const float*)d_in[0];
  const float* W1 = (const float*)d_in[1];
  const float* b1 = (const float*)d_in[2];
  const float* W2 = (const float*)d_in[3];
  const float* b2 = (const float*)d_in[4];
  const float* W3 = (const float*)d_in[5];
  const float* b3 = (const float*)d_in[6];
  unsigned short* img = (unsigned short*)d_ws;   // needs 819,200 B of workspace

  hipLaunchKernelGGL(prep_weights, dim3(800), dim3(256), 0, stream, W1, W2, W3, img);
  hipLaunchKernelGGL(ens_mlp, dim3(512), dim3(256), 0, stream,
                     x, b1, b2, b3, (const unsigned char*)img, (float*)d_out);
}

// Round 2
// 206.747 us; speedup vs baseline: 1.0134x; 1.0134x over previous
//
#include <hip/hip_runtime.h>
#include <math.h>

#define NM 5
#define NBATCH 65536
#define NCHUNK (NM * 10)   // 10 chunks per model: 4 (W1) + 4 (W2) + 2 (W3 padded to 64 rows)

typedef float f32x16 __attribute__((ext_vector_type(16)));
typedef float f32x4  __attribute__((ext_vector_type(4)));
typedef short short8 __attribute__((ext_vector_type(8)));
typedef unsigned int uint4v __attribute__((ext_vector_type(4)));
typedef unsigned int uint2v __attribute__((ext_vector_type(2)));

__device__ __forceinline__ short8 u2s(uint4v v) { union { uint4v u; short8 s; } t; t.u = v; return t.s; }

// exchange: a' = [h0: a | h1: b@h0], b' = [h0: a@h1 | h1: b]
__device__ __forceinline__ void plswap(unsigned &a, unsigned &b) {
#if __has_builtin(__builtin_amdgcn_permlane32_swap)
  uint2v r = __builtin_amdgcn_permlane32_swap(a, b, false, false);
  a = r[0]; b = r[1];
#else
  unsigned ta = (unsigned)__shfl_xor((int)a, 32, 64);
  unsigned tb = (unsigned)__shfl_xor((int)b, 32, 64);
  bool h0 = ((threadIdx.x & 63) < 32);
  unsigned na = h0 ? a : tb;
  unsigned nb = h0 ? ta : b;
  a = na; b = nb;
#endif
}

// ---------------- prep: split fp32 weights into hi/lo truncated-bf16 LDS-image in ws ----
// image: per model 163840 B; chunk c in 0..9, 16 KiB each: [hi 8 KiB][lo 8 KiB]
// plane byte(g_rel, h) = g_rel*256 + (((h>>3) ^ (g_rel & 15)) << 4) + (h&7)*2
__global__ void prep_weights(const float* __restrict__ W1, const float* __restrict__ W2,
                             const float* __restrict__ W3, unsigned short* __restrict__ img) {
  int id = blockIdx.x * 256 + threadIdx.x;
  if (id >= NM * 10 * 32 * 128) return;
  int m = id / 40960; int r = id % 40960;
  int c = r / 4096;   int r2 = r % 4096;
  int g_rel = r2 / 128; int h = r2 % 128;
  float v = 0.0f;
  if (c < 4)      { int g = c * 32 + g_rel;            v = W1[((size_t)m * 128 + g) * 128 + h]; }
  else if (c < 8) { int g = (c - 4) * 32 + g_rel;      v = W2[((size_t)m * 128 + g) * 128 + h]; }
  else            { int g = (c - 8) * 32 + g_rel; if (g < 36) v = W3[((size_t)m * 36 + g) * 128 + h]; }
  unsigned u  = __float_as_uint(v);
  unsigned hu = u & 0xFFFF0000u;
  float lo    = v - __uint_as_float(hu);
  unsigned lu = __float_as_uint(lo);
  int off = g_rel * 256 + (((h >> 3) ^ (g_rel & 15)) << 4) + (h & 7) * 2;
  size_t base = (size_t)m * 163840 + (size_t)c * 16384;
  img[(base + off) >> 1]        = (unsigned short)(hu >> 16);
  img[(base + 8192 + off) >> 1] = (unsigned short)(lu >> 16);
}

// ---------------- one GEMM layer: acc[mf] (32 rows each) = Wchunk * B + bias ------------
// NOTE: all fragment arrays passed by fixed-size reference (never pointer) so that
// post-inline SROA keeps them in VGPRs — pointer-passing put them in scratch (R1:
// 95 MB/launch of spill traffic, VGPR_Count=128).
template <int MF, typename StageF>
__device__ __forceinline__ void run_layer(int cbase, const float* bias,
                                          const uint4v (&Bh)[8], const uint4v (&Bl)[8],
                                          f32x16 (&acc)[MF], int l31, int half,
                                          const unsigned char (*wbuf)[16384],
                                          StageF&& stage) {
#pragma unroll
  for (int mf = 0; mf < MF; ++mf) {
    const int c = cbase + mf;
    stage(c + 1);                       // prefetch next chunk into other buffer
    f32x16 aA, aB;
#pragma unroll
    for (int i = 0; i < 16; ++i) { aA[i] = 0.0f; aB[i] = 0.0f; }
    if (bias) {
#pragma unroll
      for (int q = 0; q < 4; ++q) {     // row = (i&3) + 8*(i>>2) + 4*half
        f32x4 bq = *(const f32x4*)(bias + mf * 32 + q * 8 + half * 4);
#pragma unroll
        for (int r = 0; r < 4; ++r) aA[4 * q + r] = bq[r];
      }
    }
    const unsigned char* rowp = &wbuf[c & 1][0] + l31 * 256;
#pragma unroll
    for (int kk = 0; kk < 8; ++kk) {
      const int sl = (((2 * kk + half) ^ (l31 & 15)) << 4);
      short8 Ah = *(const short8*)(rowp + sl);
      short8 Al = *(const short8*)(rowp + 8192 + sl);
      if ((kk & 1) == 0) {              // two independent chains break MFMA dep-stalls
        aA = __builtin_amdgcn_mfma_f32_32x32x16_bf16(Ah, u2s(Bh[kk]), aA, 0, 0, 0);
        aA = __builtin_amdgcn_mfma_f32_32x32x16_bf16(Ah, u2s(Bl[kk]), aA, 0, 0, 0);
        aA = __builtin_amdgcn_mfma_f32_32x32x16_bf16(Al, u2s(Bh[kk]), aA, 0, 0, 0);
      } else {
        aB = __builtin_amdgcn_mfma_f32_32x32x16_bf16(Ah, u2s(Bh[kk]), aB, 0, 0, 0);
        aB = __builtin_amdgcn_mfma_f32_32x32x16_bf16(Ah, u2s(Bl[kk]), aB, 0, 0, 0);
        aB = __builtin_amdgcn_mfma_f32_32x32x16_bf16(Al, u2s(Bh[kk]), aB, 0, 0, 0);
      }
    }
#pragma unroll
    for (int i = 0; i < 16; ++i) acc[mf][i] = aA[i] + aB[i];
    __syncthreads();                    // drains our staged loads + releases old buffer
  }
}

// ---------------- C/D accumulators -> next layer's B fragments (hi/lo bf16) ------------
template <int MF, bool RELU>
__device__ __forceinline__ void cvt_to_B(const f32x16 (&acc)[MF],
                                         uint4v (&Bh)[2 * MF], uint4v (&Bl)[2 * MF]) {
#pragma unroll
  for (int mf = 0; mf < MF; ++mf) {
#pragma unroll
    for (int s = 0; s < 2; ++s) {       // kstep 2*mf+s from regs 8s..8s+7
      unsigned hu[8], lu[8];
#pragma unroll
      for (int i = 0; i < 8; ++i) {
        float v = acc[mf][8 * s + i];
        if (RELU) v = fmaxf(v, 0.0f);
        unsigned u = __float_as_uint(v);
        unsigned h = u & 0xFFFF0000u;
        hu[i] = h;
        lu[i] = __float_as_uint(v - __uint_as_float(h));
      }
      unsigned a0 = (hu[0] >> 16) | hu[1], a1 = (hu[2] >> 16) | hu[3];
      unsigned a2 = (hu[4] >> 16) | hu[5], a3 = (hu[6] >> 16) | hu[7];
      plswap(a0, a2); plswap(a1, a3);
      unsigned c0 = (lu[0] >> 16) | (lu[1] & 0xFFFF0000u), c1 = (lu[2] >> 16) | (lu[3] & 0xFFFF0000u);
      unsigned c2 = (lu[4] >> 16) | (lu[5] & 0xFFFF0000u), c3 = (lu[6] >> 16) | (lu[7] & 0xFFFF0000u);
      plswap(c0, c2); plswap(c1, c3);
      Bh[2 * mf + s] = uint4v{a0, a1, a2, a3};
      Bl[2 * mf + s] = uint4v{c0, c1, c2, c3};
    }
  }
}

// ---------------- main fused kernel ----------------------------------------------------
__global__ __launch_bounds__(256, 2)
void ens_mlp(const float* __restrict__ x,  const float* __restrict__ b1,
             const float* __restrict__ b2, const float* __restrict__ b3,
             const unsigned char* __restrict__ img, float* __restrict__ out) {
  __shared__ __align__(16) unsigned char wbuf[2][16384];   // 32 KiB W-chunk double buffer
  __shared__ float ybuf[128][37];                          // pad 36->37: conflict-free epilogue
  __shared__ float accb[256][19];                          // per-thread sm[9]/sv[9], stride 19 (odd)

  const int tid  = threadIdx.x;
  const int lane = tid & 63;
  const int wv   = tid >> 6;
  const int l31  = lane & 31;
  const int half = lane >> 5;
  const int b_loc = wv * 32 + l31;
  const size_t b_glob = (size_t)blockIdx.x * 128 + b_loc;

  auto stage = [&](int j) {
    if (j >= NCHUNK) return;
    const unsigned char* src = img + (size_t)(j / 10) * 163840 + (size_t)(j % 10) * 16384;
    unsigned char* dst = &wbuf[j & 1][0];
#pragma unroll
    for (int i = 0; i < 4; ++i) {
      int off = i * 4096 + wv * 1024;   // dest: wave-uniform base + lane*16 (linear image)
      __builtin_amdgcn_global_load_lds(
          (const __attribute__((address_space(1))) unsigned int*)(src + off + lane * 16),
          (__attribute__((address_space(3))) unsigned int*)(dst + off),
          16, 0, 0);
    }
  };

  stage(0);

#pragma unroll
  for (int i = 0; i < 18; ++i) accb[tid][i] = 0.0f;

  // x fragments (layer-1 B operand), hi/lo truncated-bf16, resident for all 5 models.
  uint4v xh[8], xl[8];
  {
    const float* xrow = x + b_glob * 128 + half * 8;
#pragma unroll
    for (int kk = 0; kk < 8; ++kk) {
      f32x4 f0 = *(const f32x4*)(xrow + kk * 16);
      f32x4 f1 = *(const f32x4*)(xrow + kk * 16 + 4);
      float f[8] = {f0[0], f0[1], f0[2], f0[3], f1[0], f1[1], f1[2], f1[3]};
      uint4v hw, lw;
#pragma unroll
      for (int jj = 0; jj < 4; ++jj) {
        unsigned ua = __float_as_uint(f[2 * jj]), ub = __float_as_uint(f[2 * jj + 1]);
        unsigned ha = ua & 0xFFFF0000u, hb = ub & 0xFFFF0000u;
        float la = f[2 * jj] - __uint_as_float(ha);
        float lb = f[2 * jj + 1] - __uint_as_float(hb);
        hw[jj] = (ha >> 16) | hb;
        lw[jj] = (__float_as_uint(la) >> 16) | (__float_as_uint(lb) & 0xFFFF0000u);
      }
      xh[kk] = hw; xl[kk] = lw;
    }
  }
  __syncthreads();   // chunk 0 ready

  for (int m = 0; m < NM; ++m) {
    const int c0 = m * 10;

    f32x16 acc1[4];
    run_layer<4>(c0, b1 + m * 128, xh, xl, acc1, l31, half, wbuf, stage);
    uint4v B2h[8], B2l[8];
    cvt_to_B<4, true>(acc1, B2h, B2l);

    f32x16 acc2[4];
    run_layer<4>(c0 + 4, b2 + m * 128, B2h, B2l, acc2, l31, half, wbuf, stage);
    uint4v B3h[8], B3l[8];
    cvt_to_B<4, true>(acc2, B3h, B3l);

    f32x16 acc3[2];
    run_layer<2>(c0 + 8, (const float*)nullptr, B3h, B3l, acc3, l31, half, wbuf, stage);

    // ---- epilogue: transpose y through LDS, combine across models --------------------
#pragma unroll
    for (int i = 0; i < 16; ++i) {
      int o = (i & 3) + 8 * (i >> 2) + 4 * half;   // 0..31
      ybuf[b_loc][o] = acc3[0][i];
    }
    if (half == 0) {
#pragma unroll
      for (int i = 0; i < 4; ++i) ybuf[b_loc][32 + i] = acc3[1][i];   // o = 32..35
    }
    __syncthreads();
    const float* b3m = b3 + m * 36;
#pragma unroll
    for (int i = 0; i < 9; ++i) {
      int e = tid + 256 * i;            // 2304 = 128 rows * 18 outputs
      int r = e / 18, o = e - 18 * r;
      float ym = ybuf[r][o] + b3m[o];
      float yv = ybuf[r][o + 18] + b3m[o + 18];
      float sp = fmaxf(yv, 0.0f) + log1pf(expf(-fabsf(yv)));   // stable softplus
      accb[tid][i]     += ym;
      accb[tid][9 + i] += sp + 1e-6f + ym * ym;
    }
    __syncthreads();                    // release ybuf for next model
  }

  const size_t rbase = (size_t)blockIdx.x * 128 * 18;
#pragma unroll
  for (int i = 0; i < 9; ++i) {
    int e = tid + 256 * i;
    float mean = accb[tid][i] * 0.2f;
    float var  = fmaxf(accb[tid][9 + i] * 0.2f - mean * mean, 0.0f) + 1e-6f;
    out[rbase + e] = mean;
    out[(size_t)NBATCH * 18 + rbase + e] = var;
  }
}

// ---------------- launcher -------------------------------------------------------------
extern "C" void kernel_launch(void* const* d_in, const int* in_sizes, int n_in,
                              void* d_out, int out_size, void* d_ws, size_t ws_size,
                              hipStream_t stream) {
  const float* x  = (const float*)d_in[0];
  const float* W1 = (const float*)d_in[1];
  const float* b1 = (const float*)d_in[2];
  const float* W2 = (const float*)d_in[3];
  const float* b2 = (const float*)d_in[4];
  const float* W3 = (const float*)d_in[5];
  const float* b3 = (const float*)d_in[6];
  unsigned short* img = (unsigned short*)d_ws;   // needs 819,200 B of workspace

  hipLaunchKernelGGL(prep_weights, dim3(800), dim3(256), 0, stream, W1, W2, W3, img);
  hipLaunchKernelGGL(ens_mlp, dim3(512), dim3(256), 0, stream,
                     x, b1, b2, b3, (const unsigned char*)img, (float*)d_out);
}